// Round 2
// baseline (2196.905 us; speedup 1.0000x reference)
//
#include <hip/hip_runtime.h>

typedef unsigned short u16;
typedef __attribute__((ext_vector_type(8))) short bf16x8;
typedef __attribute__((ext_vector_type(4))) float f32x4;

#define T_TOK 16384
#define DDIM  1024
#define HDIM  4096
#define NEXP  8

// ---------------- ws layout (bytes) ----------------
static constexpr size_t XBF_OFF  = 0;                                   // T*D bf16      = 33.5 MB
static constexpr size_t EW1T_OFF = XBF_OFF  + (size_t)T_TOK*DDIM*2;     // E*H*D bf16    = 67 MB (ew1 transposed: [e][h][d])
static constexpr size_t EW2T_OFF = EW1T_OFF + (size_t)NEXP*HDIM*DDIM*2; // E*D*H bf16    = 67 MB (ew2 transposed: [e][d][h])
static constexpr size_t TOK_OFF  = EW2T_OFF + (size_t)NEXP*DDIM*HDIM*2; // E*T int
static constexpr size_t WT_OFF   = TOK_OFF  + (size_t)NEXP*T_TOK*4;     // E*T float
static constexpr size_t CNT_OFF  = WT_OFF   + (size_t)NEXP*T_TOK*4;     // 8 int (padded 256)
static constexpr size_t BASE_OFF = CNT_OFF  + 256;                      // 8 int (padded 256)
static constexpr size_t BEFF_OFF = BASE_OFF + 256;                      // 1024 float
static constexpr size_t HBUF_OFF = BEFF_OFF + 4096;                     // aliased: gate-h fp32 (64MB) then H bf16
static constexpr size_t HBUF_ROWS = 2*T_TOK + 128;
static constexpr size_t WS_NEED_2048 = HBUF_OFF + HBUF_ROWS*(size_t)2048*2;
static constexpr size_t WS_NEED_4096 = HBUF_OFF + HBUF_ROWS*(size_t)4096*2;

__device__ __forceinline__ u16 f2bf(float f) {
  unsigned u = __float_as_uint(f);
  unsigned r = (u + 0x7FFFu + ((u >> 16) & 1u)) >> 16;   // RNE
  return (u16)r;
}

// async global->LDS, 16B per lane; LDS dest = wave-uniform base + lane*16
#define GL16(gp, lp) __builtin_amdgcn_global_load_lds( \
    (const __attribute__((address_space(1))) void*)(gp), \
    (__attribute__((address_space(3))) void*)(lp), 16, 0, 0)

// ---------------- x -> bf16 ----------------
__global__ __launch_bounds__(256) void k_convert_x(const float* __restrict__ x, u16* __restrict__ xbf, int n4) {
  int i = blockIdx.x * blockDim.x + threadIdx.x;
  int stride = gridDim.x * blockDim.x;
  for (; i < n4; i += stride) {
    float4 v = *(((const float4*)x) + i);
    uint2 pv;
    pv.x = (unsigned)f2bf(v.x) | ((unsigned)f2bf(v.y) << 16);
    pv.y = (unsigned)f2bf(v.z) | ((unsigned)f2bf(v.w) << 16);
    *(uint2*)(xbf + (size_t)i * 4) = pv;
  }
}

// ---------------- effective gate bias: b1 + snr * w1[last row] ----------------
__global__ __launch_bounds__(256) void k_bias_eff(const float* __restrict__ w1, const float* __restrict__ b1,
                                                  const float* __restrict__ snr, float* __restrict__ beff) {
  int j = blockIdx.x * 256 + threadIdx.x;
  if (j < DDIM) beff[j] = b1[j] + snr[0] * w1[(size_t)DDIM * DDIM + j];
}

// ---------------- fp32 [E][R][C] -> bf16 [E][C][R] ----------------
__global__ __launch_bounds__(256) void k_transpose_bf16(const float* __restrict__ in, u16* __restrict__ out,
                                                        int Rr, int Cc) {
  __shared__ u16 tile[64][72];
  const float* inE = in + (size_t)blockIdx.z * Rr * Cc;
  u16* outE = out + (size_t)blockIdx.z * Rr * Cc;
  int r0 = blockIdx.x * 64, c0 = blockIdx.y * 64;
  #pragma unroll
  for (int i = 0; i < 4; i++) {
    int id = threadIdx.x + i * 256;
    int r = id >> 4, cq = id & 15;
    float4 v = *(const float4*)(inE + (size_t)(r0 + r) * Cc + c0 + cq * 4);
    tile[cq*4+0][r] = f2bf(v.x);
    tile[cq*4+1][r] = f2bf(v.y);
    tile[cq*4+2][r] = f2bf(v.z);
    tile[cq*4+3][r] = f2bf(v.w);
  }
  __syncthreads();
  #pragma unroll
  for (int i = 0; i < 2; i++) {
    int id = threadIdx.x + i * 256;
    int c = id >> 3, rq = id & 7;
    *(uint4*)(outE + (size_t)(c0 + c) * Rr + r0 + rq * 8) = *(const uint4*)&tile[c][rq * 8];
  }
}

// ---------------- gate hidden: h = relu(x @ W1[:D,:] + beff), fp32 SGEMM ----------------
__global__ __launch_bounds__(256) void k_gate_h(const float* __restrict__ x, const float* __restrict__ w1,
                                                const float* __restrict__ beff, float* __restrict__ h) {
  __shared__ float As[16][132];   // [k][m], padded
  __shared__ float Bs[16][68];    // [k][n], padded
  int m0 = blockIdx.x * 128, n0 = blockIdx.y * 64;
  int tid = threadIdx.x;
  int ty = tid >> 4, tx = tid & 15;
  float acc[8][4] = {};
  for (int k0 = 0; k0 < DDIM; k0 += 16) {
    #pragma unroll
    for (int i = 0; i < 2; i++) {
      int id = tid + i * 256;
      int r = id >> 2, kq = id & 3;
      float4 v = *(const float4*)(x + (size_t)(m0 + r) * DDIM + k0 + kq * 4);
      As[kq*4+0][r] = v.x; As[kq*4+1][r] = v.y; As[kq*4+2][r] = v.z; As[kq*4+3][r] = v.w;
    }
    {
      int kk = tid >> 4, nq = tid & 15;
      *(float4*)&Bs[kk][nq*4] = *(const float4*)(w1 + (size_t)(k0 + kk) * DDIM + n0 + nq * 4);
    }
    __syncthreads();
    #pragma unroll
    for (int kk = 0; kk < 16; kk++) {
      float a[8], b[4];
      *(float4*)&a[0] = *(const float4*)&As[kk][ty*8];
      *(float4*)&a[4] = *(const float4*)&As[kk][ty*8+4];
      *(float4*)&b[0] = *(const float4*)&Bs[kk][tx*4];
      #pragma unroll
      for (int mi = 0; mi < 8; mi++)
        #pragma unroll
        for (int ni = 0; ni < 4; ni++)
          acc[mi][ni] = fmaf(a[mi], b[ni], acc[mi][ni]);
    }
    __syncthreads();
  }
  #pragma unroll
  for (int mi = 0; mi < 8; mi++) {
    int row = m0 + ty * 8 + mi;
    float4 o;
    o.x = fmaxf(acc[mi][0] + beff[n0 + tx*4 + 0], 0.f);
    o.y = fmaxf(acc[mi][1] + beff[n0 + tx*4 + 1], 0.f);
    o.z = fmaxf(acc[mi][2] + beff[n0 + tx*4 + 2], 0.f);
    o.w = fmaxf(acc[mi][3] + beff[n0 + tx*4 + 3], 0.f);
    *(float4*)(h + (size_t)row * DDIM + n0 + tx * 4) = o;
  }
}

// ---------------- logits + gumbel softmax + top2 + routing ----------------
__global__ __launch_bounds__(256) void k_gate_logits(const float* __restrict__ h, const float* __restrict__ w2,
    const float* __restrict__ b2, const float* __restrict__ gu, float* __restrict__ scores,
    float* __restrict__ maskp, int* __restrict__ tokl, float* __restrict__ wtl, int* __restrict__ cnts) {
  int wid = threadIdx.x >> 6, lane = threadIdx.x & 63;
  int t = blockIdx.x * 4 + wid;
  const float* hr = h + (size_t)t * DDIM;
  float acc[8] = {0,0,0,0,0,0,0,0};
  for (int kk = 0; kk < DDIM / 64; kk++) {
    int k = kk * 64 + lane;
    float hv = hr[k];
    float4 wa = *(const float4*)(w2 + (size_t)k * 8);
    float4 wb = *(const float4*)(w2 + (size_t)k * 8 + 4);
    acc[0] += hv * wa.x; acc[1] += hv * wa.y; acc[2] += hv * wa.z; acc[3] += hv * wa.w;
    acc[4] += hv * wb.x; acc[5] += hv * wb.y; acc[6] += hv * wb.z; acc[7] += hv * wb.w;
  }
  #pragma unroll
  for (int e = 0; e < 8; e++) {
    #pragma unroll
    for (int off = 32; off > 0; off >>= 1) acc[e] += __shfl_down(acc[e], off);
  }
  if (lane == 0) {
    float sc[8];
    float m = -1e30f;
    #pragma unroll
    for (int e = 0; e < 8; e++) {
      float u = gu[(size_t)t * 8 + e];
      float g = -logf(-logf(u + 1e-9f) + 1e-9f);
      sc[e] = acc[e] + b2[e] + g;          // TAU = 1.0
      m = fmaxf(m, sc[e]);
    }
    float s = 0.f;
    #pragma unroll
    for (int e = 0; e < 8; e++) { sc[e] = expf(sc[e] - m); s += sc[e]; }
    float inv = 1.f / s;
    #pragma unroll
    for (int e = 0; e < 8; e++) { sc[e] *= inv; scores[(size_t)t * 8 + e] = sc[e]; }
    int i1 = 0;
    #pragma unroll
    for (int e = 1; e < 8; e++) if (sc[e] > sc[i1]) i1 = e;        // strict > => lowest index on ties (matches top_k)
    int i2 = (i1 == 0) ? 1 : 0;
    #pragma unroll
    for (int e = 0; e < 8; e++) if (e != i1 && sc[e] > sc[i2]) i2 = e;
    #pragma unroll
    for (int e = 0; e < 8; e++) maskp[(size_t)t * 8 + e] = (e == i1 || e == i2) ? 1.f : 0.f;
    int p1 = atomicAdd(&cnts[i1], 1);
    tokl[i1 * T_TOK + p1] = t; wtl[i1 * T_TOK + p1] = sc[i1];
    int p2 = atomicAdd(&cnts[i2], 1);
    tokl[i2 * T_TOK + p2] = t; wtl[i2 * T_TOK + p2] = sc[i2];
  }
}

__global__ void k_scan(const int* __restrict__ cnts, int* __restrict__ basep) {
  if (threadIdx.x == 0 && blockIdx.x == 0) {
    int s = 0;
    for (int e = 0; e < NEXP; e++) { basep[e] = s; s += cnts[e]; }
  }
}

// MFMA compute on one 64-K LDS tile (swizzled layout: LDS[r][p] = global[r][p ^ (r&7)])
#define MFMA_STEP(Abuf, Bbuf)                                                     \
  do {                                                                            \
    _Pragma("unroll")                                                             \
    for (int ks = 0; ks < 2; ks++) {                                              \
      const int chk = ks * 4 + (lane >> 4);                                       \
      bf16x8 af[4], bfr[4];                                                       \
      _Pragma("unroll")                                                           \
      for (int m = 0; m < 4; m++) {                                               \
        int row = wr + m * 16 + (lane & 15);                                      \
        af[m] = *(const bf16x8*)&(Abuf)[row * 64 + ((chk ^ (row & 7)) * 8)];      \
      }                                                                           \
      _Pragma("unroll")                                                           \
      for (int n = 0; n < 4; n++) {                                               \
        int col = wc + n * 16 + (lane & 15);                                      \
        bfr[n] = *(const bf16x8*)&(Bbuf)[col * 64 + ((chk ^ (col & 7)) * 8)];     \
      }                                                                           \
      _Pragma("unroll")                                                           \
      for (int m = 0; m < 4; m++)                                                 \
        _Pragma("unroll")                                                         \
        for (int n = 0; n < 4; n++)                                               \
          acc[m][n] = __builtin_amdgcn_mfma_f32_16x16x32_bf16(af[m], bfr[n], acc[m][n], 0, 0, 0); \
    }                                                                             \
  } while (0)

// ---------------- FFN pass 1: H[g, c0+hc] = relu(Xg @ ew1[e] + eb1) ----------------
// 128x128 tile, BK=64, 2-phase double-buffered global_load_lds staging.
__global__ __launch_bounds__(256) void k_ffn1(const u16* __restrict__ xbf, const u16* __restrict__ ew1t,
    const float* __restrict__ eb1, const int* __restrict__ tokl, const int* __restrict__ cnts,
    const int* __restrict__ basep, u16* __restrict__ hbuf, int c0, int HCcur) {
  const int e = blockIdx.z;
  const int nt = cnts[e];
  const int r0 = blockIdx.x * 128;
  if (r0 >= nt) return;
  const int hc0 = blockIdx.y * 128;

  __shared__ u16 As[2][8192];
  __shared__ u16 Bs[2][8192];
  __shared__ int toks[128];

  const int tid = threadIdx.x;
  const int wid = tid >> 6, lane = tid & 63;
  if (tid < 128) {
    int row = r0 + tid;
    toks[tid] = tokl[e * T_TOK + (row < nt ? row : nt - 1)];
  }
  __syncthreads();

  // staging source pointers: lane covers row rr = seg*8 + (lane>>3), global chunk (lane&7)^(lane>>3)
  const int cXor = ((lane & 7) ^ (lane >> 3)) * 8;   // u16 offset within a 64-elem row
  const u16* gA[4];
  const u16* gB[4];
  #pragma unroll
  for (int i = 0; i < 4; i++) {
    int seg = wid * 4 + i;
    int rr = seg * 8 + (lane >> 3);
    gA[i] = xbf + (size_t)toks[rr] * DDIM + cXor;
    gB[i] = ew1t + ((size_t)e * HDIM + c0 + hc0 + rr) * DDIM + cXor;
  }

  const int wr = (wid >> 1) * 64, wc = (wid & 1) * 64;
  f32x4 acc[4][4] = {};

#define STAGE_F1(buf, kt)                                   \
  do {                                                      \
    _Pragma("unroll")                                       \
    for (int i = 0; i < 4; i++) {                           \
      int seg = wid * 4 + i;                                \
      GL16(gA[i] + (kt), &As[buf][seg * 512]);              \
      GL16(gB[i] + (kt), &Bs[buf][seg * 512]);              \
    }                                                       \
  } while (0)

  STAGE_F1(0, 0);
  __syncthreads();
  int cur = 0;
  for (int kt = 64; kt < DDIM; kt += 64) {
    STAGE_F1(cur ^ 1, kt);
    MFMA_STEP(As[cur], Bs[cur]);
    __syncthreads();
    cur ^= 1;
  }
  MFMA_STEP(As[cur], Bs[cur]);

  const int g0 = basep[e];
  #pragma unroll
  for (int m = 0; m < 4; m++) {
    int rt0 = wr + m * 16 + ((lane >> 4) << 2);
    #pragma unroll
    for (int ri = 0; ri < 4; ri++) {
      int rE = r0 + rt0 + ri;
      if (rE < nt) {
        size_t grow = (size_t)(g0 + rE) * HCcur;
        #pragma unroll
        for (int n = 0; n < 4; n++) {
          int collocal = hc0 + wc + n * 16 + (lane & 15);
          float v = acc[m][n][ri] + eb1[e * HDIM + c0 + collocal];
          hbuf[grow + collocal] = f2bf(fmaxf(v, 0.f));
        }
      }
    }
  }
#undef STAGE_F1
}

// ---------------- FFN pass 2: out[t] += w * (H[g] @ ew2[e] + eb2) ----------------
__global__ __launch_bounds__(256) void k_ffn2(const u16* __restrict__ hbuf, const u16* __restrict__ ew2t,
    const float* __restrict__ eb2, const int* __restrict__ tokl, const float* __restrict__ wtl,
    const int* __restrict__ cnts, const int* __restrict__ basep, float* __restrict__ out,
    int c0, int HCcur) {
  const int e = blockIdx.z;
  const int nt = cnts[e];
  const int r0 = blockIdx.x * 128;
  if (r0 >= nt) return;
  const int d0 = blockIdx.y * 128;

  __shared__ u16 As[2][8192];
  __shared__ u16 Bs[2][8192];
  __shared__ int toks[128];
  __shared__ float wts[128];

  const int tid = threadIdx.x;
  const int wid = tid >> 6, lane = tid & 63;
  const int g0 = basep[e];
  if (tid < 128) {
    int row = r0 + tid;
    int cr = row < nt ? row : nt - 1;
    toks[tid] = tokl[e * T_TOK + cr];
    wts[tid]  = wtl[e * T_TOK + cr];
  }

  const int cXor = ((lane & 7) ^ (lane >> 3)) * 8;
  const u16* gA[4];
  const u16* gB[4];
  #pragma unroll
  for (int i = 0; i < 4; i++) {
    int seg = wid * 4 + i;
    int rr = seg * 8 + (lane >> 3);
    gA[i] = hbuf + (size_t)(g0 + r0 + rr) * HCcur + cXor;
    gB[i] = ew2t + ((size_t)e * DDIM + d0 + rr) * HDIM + c0 + cXor;
  }

  const int wr = (wid >> 1) * 64, wc = (wid & 1) * 64;
  f32x4 acc[4][4] = {};

#define STAGE_F2(buf, kt)                                   \
  do {                                                      \
    _Pragma("unroll")                                       \
    for (int i = 0; i < 4; i++) {                           \
      int seg = wid * 4 + i;                                \
      GL16(gA[i] + (kt), &As[buf][seg * 512]);              \
      GL16(gB[i] + (kt), &Bs[buf][seg * 512]);              \
    }                                                       \
  } while (0)

  STAGE_F2(0, 0);
  __syncthreads();
  int cur = 0;
  for (int kt = 64; kt < HCcur; kt += 64) {
    STAGE_F2(cur ^ 1, kt);
    MFMA_STEP(As[cur], Bs[cur]);
    __syncthreads();
    cur ^= 1;
  }
  MFMA_STEP(As[cur], Bs[cur]);

  #pragma unroll
  for (int m = 0; m < 4; m++) {
    int rt0 = wr + m * 16 + ((lane >> 4) << 2);
    #pragma unroll
    for (int ri = 0; ri < 4; ri++) {
      int rt = rt0 + ri;
      int rE = r0 + rt;
      if (rE < nt) {
        int t = toks[rt];
        float w = wts[rt];
        #pragma unroll
        for (int n = 0; n < 4; n++) {
          int col = d0 + wc + n * 16 + (lane & 15);
          float v = acc[m][n][ri];
          if (c0 == 0) v += eb2[e * DDIM + col];
          atomicAdd(&out[(size_t)t * DDIM + col], w * v);
        }
      }
    }
  }
#undef STAGE_F2
}

// ---------------- launch ----------------
extern "C" void kernel_launch(void* const* d_in, const int* in_sizes, int n_in,
                              void* d_out, int out_size, void* d_ws, size_t ws_size,
                              hipStream_t stream) {
  const float* x   = (const float*)d_in[0];
  const float* snr = (const float*)d_in[1];
  const float* gu  = (const float*)d_in[2];
  const float* gw1 = (const float*)d_in[3];
  const float* gb1 = (const float*)d_in[4];
  const float* gw2 = (const float*)d_in[5];
  const float* gb2 = (const float*)d_in[6];
  const float* ew1 = (const float*)d_in[7];
  const float* eb1 = (const float*)d_in[8];
  const float* ew2 = (const float*)d_in[9];
  const float* eb2 = (const float*)d_in[10];

  if (ws_size < WS_NEED_2048) return;  // outputs stay poisoned -> loud failure signal
  const int HCcur = (ws_size >= WS_NEED_4096) ? 4096 : 2048;   // single-chunk if ws permits

  char* ws = (char*)d_ws;
  u16*   xbf   = (u16*)(ws + XBF_OFF);
  u16*   ew1t  = (u16*)(ws + EW1T_OFF);
  u16*   ew2t  = (u16*)(ws + EW2T_OFF);
  int*   tokl  = (int*)(ws + TOK_OFF);
  float* wtl   = (float*)(ws + WT_OFF);
  int*   cnts  = (int*)(ws + CNT_OFF);
  int*   basep = (int*)(ws + BASE_OFF);
  float* beff  = (float*)(ws + BEFF_OFF);
  float* hgate = (float*)(ws + HBUF_OFF);   // fp32 gate hidden, aliased with hbuf (consumed before FFN1)
  u16*   hbuf  = (u16*)(ws + HBUF_OFF);

  float* out    = (float*)d_out;
  float* scores = out + (size_t)T_TOK * DDIM;
  float* maskp  = scores + (size_t)T_TOK * NEXP;

  hipMemsetAsync(out, 0, (size_t)T_TOK * DDIM * sizeof(float), stream);  // atomics accumulate into this
  hipMemsetAsync(cnts, 0, NEXP * sizeof(int), stream);

  k_convert_x<<<2048, 256, 0, stream>>>(x, xbf, T_TOK * DDIM / 4);
  k_bias_eff<<<(DDIM + 255) / 256, 256, 0, stream>>>(gw1, gb1, snr, beff);
  k_transpose_bf16<<<dim3(DDIM / 64, HDIM / 64, NEXP), 256, 0, stream>>>(ew1, ew1t, DDIM, HDIM);
  k_transpose_bf16<<<dim3(HDIM / 64, DDIM / 64, NEXP), 256, 0, stream>>>(ew2, ew2t, HDIM, DDIM);
  k_gate_h<<<dim3(T_TOK / 128, DDIM / 64), 256, 0, stream>>>(x, gw1, beff, hgate);
  k_gate_logits<<<T_TOK / 4, 256, 0, stream>>>(hgate, gw2, gb2, gu, scores, maskp, tokl, wtl, cnts);
  k_scan<<<1, 64, 0, stream>>>(cnts, basep);

  for (int c = 0; c < HDIM / HCcur; c++) {
    k_ffn1<<<dim3(T_TOK / 128, HCcur / 128, NEXP), 256, 0, stream>>>(xbf, ew1t, eb1, tokl, cnts, basep, hbuf, c * HCcur, HCcur);
    k_ffn2<<<dim3(T_TOK / 128, DDIM / 128, NEXP), 256, 0, stream>>>(hbuf, ew2t, eb2, tokl, wtl, cnts, basep, out, c * HCcur, HCcur);
  }
}

// Round 3
// 1974.278 us; speedup vs baseline: 1.1128x; 1.1128x over previous
//
#include <hip/hip_runtime.h>

typedef unsigned short u16;
typedef __attribute__((ext_vector_type(8))) short bf16x8;
typedef __attribute__((ext_vector_type(4))) float f32x4;

#define T_TOK 16384
#define DDIM  1024
#define HDIM  4096
#define NEXP  8

// ---------------- ws layout (bytes) ----------------
static constexpr size_t XBF_OFF  = 0;                                   // T*D bf16      = 33.5 MB
static constexpr size_t EW1T_OFF = XBF_OFF  + (size_t)T_TOK*DDIM*2;     // E*H*D bf16    = 67 MB (ew1 transposed: [e][h][d])
static constexpr size_t EW2T_OFF = EW1T_OFF + (size_t)NEXP*HDIM*DDIM*2; // E*D*H bf16    = 67 MB (ew2 transposed: [e][d][h])
static constexpr size_t TOK_OFF  = EW2T_OFF + (size_t)NEXP*DDIM*HDIM*2; // E*T int
static constexpr size_t WT_OFF   = TOK_OFF  + (size_t)NEXP*T_TOK*4;     // E*T float
static constexpr size_t CNT_OFF  = WT_OFF   + (size_t)NEXP*T_TOK*4;     // 8 int (padded 256)
static constexpr size_t BASE_OFF = CNT_OFF  + 256;                      // 8 int (padded 256)
static constexpr size_t BEFF_OFF = BASE_OFF + 256;                      // 1024 float
static constexpr size_t HBUF_OFF = BEFF_OFF + 4096;                     // aliased: gate-h fp32 (64MB) then H bf16
static constexpr size_t HBUF_ROWS = 2*T_TOK + 128;
static constexpr size_t WS_NEED_2048 = HBUF_OFF + HBUF_ROWS*(size_t)2048*2;
static constexpr size_t WS_NEED_4096 = HBUF_OFF + HBUF_ROWS*(size_t)4096*2;

__device__ __forceinline__ u16 f2bf(float f) {
  unsigned u = __float_as_uint(f);
  unsigned r = (u + 0x7FFFu + ((u >> 16) & 1u)) >> 16;   // RNE
  return (u16)r;
}

// async global->LDS, 16B per lane; LDS dest = wave-uniform base + lane*16
#define GL16(gp, lp) __builtin_amdgcn_global_load_lds( \
    (const __attribute__((address_space(1))) void*)(gp), \
    (__attribute__((address_space(3))) void*)(lp), 16, 0, 0)

// ---------------- x -> bf16 ----------------
__global__ __launch_bounds__(256) void k_convert_x(const float* __restrict__ x, u16* __restrict__ xbf, int n4) {
  int i = blockIdx.x * blockDim.x + threadIdx.x;
  int stride = gridDim.x * blockDim.x;
  for (; i < n4; i += stride) {
    float4 v = *(((const float4*)x) + i);
    uint2 pv;
    pv.x = (unsigned)f2bf(v.x) | ((unsigned)f2bf(v.y) << 16);
    pv.y = (unsigned)f2bf(v.z) | ((unsigned)f2bf(v.w) << 16);
    *(uint2*)(xbf + (size_t)i * 4) = pv;
  }
}

// ---------------- effective gate bias: b1 + snr * w1[last row] ----------------
__global__ __launch_bounds__(256) void k_bias_eff(const float* __restrict__ w1, const float* __restrict__ b1,
                                                  const float* __restrict__ snr, float* __restrict__ beff) {
  int j = blockIdx.x * 256 + threadIdx.x;
  if (j < DDIM) beff[j] = b1[j] + snr[0] * w1[(size_t)DDIM * DDIM + j];
}

// ---------------- fp32 [E][R][C] -> bf16 [E][C][R] ----------------
__global__ __launch_bounds__(256) void k_transpose_bf16(const float* __restrict__ in, u16* __restrict__ out,
                                                        int Rr, int Cc) {
  __shared__ u16 tile[64][72];
  const float* inE = in + (size_t)blockIdx.z * Rr * Cc;
  u16* outE = out + (size_t)blockIdx.z * Rr * Cc;
  int r0 = blockIdx.x * 64, c0 = blockIdx.y * 64;
  #pragma unroll
  for (int i = 0; i < 4; i++) {
    int id = threadIdx.x + i * 256;
    int r = id >> 4, cq = id & 15;
    float4 v = *(const float4*)(inE + (size_t)(r0 + r) * Cc + c0 + cq * 4);
    tile[cq*4+0][r] = f2bf(v.x);
    tile[cq*4+1][r] = f2bf(v.y);
    tile[cq*4+2][r] = f2bf(v.z);
    tile[cq*4+3][r] = f2bf(v.w);
  }
  __syncthreads();
  #pragma unroll
  for (int i = 0; i < 2; i++) {
    int id = threadIdx.x + i * 256;
    int c = id >> 3, rq = id & 7;
    *(uint4*)(outE + (size_t)(c0 + c) * Rr + r0 + rq * 8) = *(const uint4*)&tile[c][rq * 8];
  }
}

// ---------------- gate hidden: h = relu(x @ W1[:D,:] + beff), fp32 SGEMM ----------------
// 128x128 tile, 256 threads (16x16), 8x8 per thread, BK=32, single-buffer 2-barrier loop.
__global__ __launch_bounds__(256) void k_gate_h(const float* __restrict__ x, const float* __restrict__ w1,
                                                const float* __restrict__ beff, float* __restrict__ h) {
  __shared__ float As[32][132];   // [k][m]
  __shared__ float B0s[32][68];   // [k][n low half: col = nq*8+0..3 -> B0s[k][nq*4+..]]
  __shared__ float B1s[32][68];   // [k][n high half: col = nq*8+4..7]
  int m0 = blockIdx.x * 128, n0 = blockIdx.y * 128;
  int tid = threadIdx.x;
  int ty = tid >> 4, tx = tid & 15;
  float acc[8][8] = {};
  for (int k0 = 0; k0 < DDIM; k0 += 32) {
    // stage A: 128 rows x 32 k
    #pragma unroll
    for (int i = 0; i < 4; i++) {
      int id = tid + i * 256;
      int r = id >> 3, kq = id & 7;
      float4 v = *(const float4*)(x + (size_t)(m0 + r) * DDIM + k0 + kq * 4);
      As[kq*4+0][r] = v.x; As[kq*4+1][r] = v.y; As[kq*4+2][r] = v.z; As[kq*4+3][r] = v.w;
    }
    // stage B: 32 rows x 128 cols
    #pragma unroll
    for (int i = 0; i < 2; i++) {
      int id = tid + i * 256;
      int kk = id >> 4, nq = id & 15;
      float4 v0 = *(const float4*)(w1 + (size_t)(k0 + kk) * DDIM + n0 + nq * 8);
      float4 v1 = *(const float4*)(w1 + (size_t)(k0 + kk) * DDIM + n0 + nq * 8 + 4);
      *(float4*)&B0s[kk][nq*4] = v0;
      *(float4*)&B1s[kk][nq*4] = v1;
    }
    __syncthreads();
    #pragma unroll
    for (int kk = 0; kk < 32; kk++) {
      float a[8], b[8];
      *(float4*)&a[0] = *(const float4*)&As[kk][ty*8];
      *(float4*)&a[4] = *(const float4*)&As[kk][ty*8+4];
      *(float4*)&b[0] = *(const float4*)&B0s[kk][tx*4];
      *(float4*)&b[4] = *(const float4*)&B1s[kk][tx*4];
      #pragma unroll
      for (int mi = 0; mi < 8; mi++)
        #pragma unroll
        for (int ni = 0; ni < 8; ni++)
          acc[mi][ni] = fmaf(a[mi], b[ni], acc[mi][ni]);
    }
    __syncthreads();
  }
  #pragma unroll
  for (int mi = 0; mi < 8; mi++) {
    int row = m0 + ty * 8 + mi;
    int col = n0 + tx * 8;
    float4 o0, o1;
    o0.x = fmaxf(acc[mi][0] + beff[col + 0], 0.f);
    o0.y = fmaxf(acc[mi][1] + beff[col + 1], 0.f);
    o0.z = fmaxf(acc[mi][2] + beff[col + 2], 0.f);
    o0.w = fmaxf(acc[mi][3] + beff[col + 3], 0.f);
    o1.x = fmaxf(acc[mi][4] + beff[col + 4], 0.f);
    o1.y = fmaxf(acc[mi][5] + beff[col + 5], 0.f);
    o1.z = fmaxf(acc[mi][6] + beff[col + 6], 0.f);
    o1.w = fmaxf(acc[mi][7] + beff[col + 7], 0.f);
    *(float4*)(h + (size_t)row * DDIM + col) = o0;
    *(float4*)(h + (size_t)row * DDIM + col + 4) = o1;
  }
}

// ---------------- logits + gumbel softmax + top2 + routing ----------------
__global__ __launch_bounds__(256) void k_gate_logits(const float* __restrict__ h, const float* __restrict__ w2,
    const float* __restrict__ b2, const float* __restrict__ gu, float* __restrict__ scores,
    float* __restrict__ maskp, int* __restrict__ tokl, float* __restrict__ wtl, int* __restrict__ cnts) {
  int wid = threadIdx.x >> 6, lane = threadIdx.x & 63;
  int t = blockIdx.x * 4 + wid;
  const float* hr = h + (size_t)t * DDIM;
  float acc[8] = {0,0,0,0,0,0,0,0};
  for (int kk = 0; kk < DDIM / 64; kk++) {
    int k = kk * 64 + lane;
    float hv = hr[k];
    float4 wa = *(const float4*)(w2 + (size_t)k * 8);
    float4 wb = *(const float4*)(w2 + (size_t)k * 8 + 4);
    acc[0] += hv * wa.x; acc[1] += hv * wa.y; acc[2] += hv * wa.z; acc[3] += hv * wa.w;
    acc[4] += hv * wb.x; acc[5] += hv * wb.y; acc[6] += hv * wb.z; acc[7] += hv * wb.w;
  }
  #pragma unroll
  for (int e = 0; e < 8; e++) {
    #pragma unroll
    for (int off = 32; off > 0; off >>= 1) acc[e] += __shfl_down(acc[e], off);
  }
  if (lane == 0) {
    float sc[8];
    float m = -1e30f;
    #pragma unroll
    for (int e = 0; e < 8; e++) {
      float u = gu[(size_t)t * 8 + e];
      float g = -logf(-logf(u + 1e-9f) + 1e-9f);
      sc[e] = acc[e] + b2[e] + g;          // TAU = 1.0
      m = fmaxf(m, sc[e]);
    }
    float s = 0.f;
    #pragma unroll
    for (int e = 0; e < 8; e++) { sc[e] = expf(sc[e] - m); s += sc[e]; }
    float inv = 1.f / s;
    #pragma unroll
    for (int e = 0; e < 8; e++) { sc[e] *= inv; scores[(size_t)t * 8 + e] = sc[e]; }
    int i1 = 0;
    #pragma unroll
    for (int e = 1; e < 8; e++) if (sc[e] > sc[i1]) i1 = e;        // strict > => lowest index on ties (matches top_k)
    int i2 = (i1 == 0) ? 1 : 0;
    #pragma unroll
    for (int e = 0; e < 8; e++) if (e != i1 && sc[e] > sc[i2]) i2 = e;
    #pragma unroll
    for (int e = 0; e < 8; e++) maskp[(size_t)t * 8 + e] = (e == i1 || e == i2) ? 1.f : 0.f;
    int p1 = atomicAdd(&cnts[i1], 1);
    tokl[i1 * T_TOK + p1] = t; wtl[i1 * T_TOK + p1] = sc[i1];
    int p2 = atomicAdd(&cnts[i2], 1);
    tokl[i2 * T_TOK + p2] = t; wtl[i2 * T_TOK + p2] = sc[i2];
  }
}

__global__ void k_scan(const int* __restrict__ cnts, int* __restrict__ basep) {
  if (threadIdx.x == 0 && blockIdx.x == 0) {
    int s = 0;
    for (int e = 0; e < NEXP; e++) { basep[e] = s; s += cnts[e]; }
  }
}

// MFMA compute on one 64-K LDS tile (swizzled layout: LDS[r][p] = global[r][p ^ (r&7)])
#define MFMA_STEP(Abuf, Bbuf)                                                     \
  do {                                                                            \
    _Pragma("unroll")                                                             \
    for (int ks = 0; ks < 2; ks++) {                                              \
      const int chk = ks * 4 + (lane >> 4);                                       \
      bf16x8 af[4], bfr[4];                                                       \
      _Pragma("unroll")                                                           \
      for (int m = 0; m < 4; m++) {                                               \
        int row = wr + m * 16 + (lane & 15);                                      \
        af[m] = *(const bf16x8*)&(Abuf)[row * 64 + ((chk ^ (row & 7)) * 8)];      \
      }                                                                           \
      _Pragma("unroll")                                                           \
      for (int n = 0; n < 4; n++) {                                               \
        int col = wc + n * 16 + (lane & 15);                                      \
        bfr[n] = *(const bf16x8*)&(Bbuf)[col * 64 + ((chk ^ (col & 7)) * 8)];     \
      }                                                                           \
      _Pragma("unroll")                                                           \
      for (int m = 0; m < 4; m++)                                                 \
        _Pragma("unroll")                                                         \
        for (int n = 0; n < 4; n++)                                               \
          acc[m][n] = __builtin_amdgcn_mfma_f32_16x16x32_bf16(af[m], bfr[n], acc[m][n], 0, 0, 0); \
    }                                                                             \
  } while (0)

// ---------------- FFN pass 1: H[g, c0+hc] = relu(Xg @ ew1[e] + eb1) ----------------
// m97 structure: 128x128 tile, BK=64, SINGLE-buffer global_load_lds, 2 barriers/K-step.
__global__ __launch_bounds__(256) void k_ffn1(const u16* __restrict__ xbf, const u16* __restrict__ ew1t,
    const float* __restrict__ eb1, const int* __restrict__ tokl, const int* __restrict__ cnts,
    const int* __restrict__ basep, u16* __restrict__ hbuf, int c0, int HCcur) {
  const int e = blockIdx.z;
  const int nt = cnts[e];
  const int r0 = blockIdx.x * 128;
  if (r0 >= nt) return;
  const int hc0 = blockIdx.y * 128;

  __shared__ u16 As[8192];
  __shared__ u16 Bs[8192];
  __shared__ int toks[128];

  const int tid = threadIdx.x;
  const int wid = tid >> 6, lane = tid & 63;
  if (tid < 128) {
    int row = r0 + tid;
    toks[tid] = tokl[e * T_TOK + (row < nt ? row : nt - 1)];
  }
  __syncthreads();

  // staging source: lane covers row rr = seg*8 + (lane>>3), pre-swizzled global chunk (lane&7)^(lane>>3)
  const int cXor = ((lane & 7) ^ (lane >> 3)) * 8;   // u16 offset within a 64-elem row
  const u16* gA[4];
  const u16* gB[4];
  #pragma unroll
  for (int i = 0; i < 4; i++) {
    int seg = wid * 4 + i;
    int rr = seg * 8 + (lane >> 3);
    gA[i] = xbf + (size_t)toks[rr] * DDIM + cXor;
    gB[i] = ew1t + ((size_t)e * HDIM + c0 + hc0 + rr) * DDIM + cXor;
  }

  const int wr = (wid >> 1) * 64, wc = (wid & 1) * 64;
  f32x4 acc[4][4] = {};

#define STAGE_F1(kt)                                        \
  do {                                                      \
    _Pragma("unroll")                                       \
    for (int i = 0; i < 4; i++) {                           \
      int seg = wid * 4 + i;                                \
      GL16(gA[i] + (kt), &As[seg * 512]);                   \
      GL16(gB[i] + (kt), &Bs[seg * 512]);                   \
    }                                                       \
  } while (0)

  STAGE_F1(0);
  for (int kt = 64; kt < DDIM; kt += 64) {
    __syncthreads();          // drains vmcnt(0): stage complete
    MFMA_STEP(As, Bs);
    __syncthreads();          // all LDS reads done before overwrite
    STAGE_F1(kt);
  }
  __syncthreads();
  MFMA_STEP(As, Bs);

  const int g0 = basep[e];
  #pragma unroll
  for (int m = 0; m < 4; m++) {
    int rt0 = wr + m * 16 + ((lane >> 4) << 2);
    #pragma unroll
    for (int ri = 0; ri < 4; ri++) {
      int rE = r0 + rt0 + ri;
      if (rE < nt) {
        size_t grow = (size_t)(g0 + rE) * HCcur;
        #pragma unroll
        for (int n = 0; n < 4; n++) {
          int collocal = hc0 + wc + n * 16 + (lane & 15);
          float v = acc[m][n][ri] + eb1[e * HDIM + c0 + collocal];
          hbuf[grow + collocal] = f2bf(fmaxf(v, 0.f));
        }
      }
    }
  }
#undef STAGE_F1
}

// ---------------- FFN pass 2: out[t] += w * (H[g] @ ew2[e] + eb2) ----------------
__global__ __launch_bounds__(256) void k_ffn2(const u16* __restrict__ hbuf, const u16* __restrict__ ew2t,
    const float* __restrict__ eb2, const int* __restrict__ tokl, const float* __restrict__ wtl,
    const int* __restrict__ cnts, const int* __restrict__ basep, float* __restrict__ out,
    int c0, int HCcur) {
  const int e = blockIdx.z;
  const int nt = cnts[e];
  const int r0 = blockIdx.x * 128;
  if (r0 >= nt) return;
  const int d0 = blockIdx.y * 128;

  __shared__ u16 As[8192];
  __shared__ u16 Bs[8192];
  __shared__ int toks[128];
  __shared__ float wts[128];

  const int tid = threadIdx.x;
  const int wid = tid >> 6, lane = tid & 63;
  const int g0 = basep[e];
  if (tid < 128) {
    int row = r0 + tid;
    int cr = row < nt ? row : nt - 1;
    toks[tid] = tokl[e * T_TOK + cr];
    wts[tid]  = wtl[e * T_TOK + cr];
  }

  const int cXor = ((lane & 7) ^ (lane >> 3)) * 8;
  const u16* gA[4];
  const u16* gB[4];
  #pragma unroll
  for (int i = 0; i < 4; i++) {
    int seg = wid * 4 + i;
    int rr = seg * 8 + (lane >> 3);
    gA[i] = hbuf + (size_t)(g0 + r0 + rr) * HCcur + cXor;
    gB[i] = ew2t + ((size_t)e * DDIM + d0 + rr) * HDIM + c0 + cXor;
  }

  const int wr = (wid >> 1) * 64, wc = (wid & 1) * 64;
  f32x4 acc[4][4] = {};

#define STAGE_F2(kt)                                        \
  do {                                                      \
    _Pragma("unroll")                                       \
    for (int i = 0; i < 4; i++) {                           \
      int seg = wid * 4 + i;                                \
      GL16(gA[i] + (kt), &As[seg * 512]);                   \
      GL16(gB[i] + (kt), &Bs[seg * 512]);                   \
    }                                                       \
  } while (0)

  STAGE_F2(0);
  for (int kt = 64; kt < HCcur; kt += 64) {
    __syncthreads();
    MFMA_STEP(As, Bs);
    __syncthreads();
    STAGE_F2(kt);
  }
  __syncthreads();
  MFMA_STEP(As, Bs);

  #pragma unroll
  for (int m = 0; m < 4; m++) {
    int rt0 = wr + m * 16 + ((lane >> 4) << 2);
    #pragma unroll
    for (int ri = 0; ri < 4; ri++) {
      int rt = rt0 + ri;
      int rE = r0 + rt;
      if (rE < nt) {
        int t = toks[rt];
        float w = wts[rt];
        #pragma unroll
        for (int n = 0; n < 4; n++) {
          int col = d0 + wc + n * 16 + (lane & 15);
          float v = acc[m][n][ri];
          if (c0 == 0) v += eb2[e * DDIM + col];
          atomicAdd(&out[(size_t)t * DDIM + col], w * v);
        }
      }
    }
  }
#undef STAGE_F2
}

// ---------------- launch ----------------
extern "C" void kernel_launch(void* const* d_in, const int* in_sizes, int n_in,
                              void* d_out, int out_size, void* d_ws, size_t ws_size,
                              hipStream_t stream) {
  const float* x   = (const float*)d_in[0];
  const float* snr = (const float*)d_in[1];
  const float* gu  = (const float*)d_in[2];
  const float* gw1 = (const float*)d_in[3];
  const float* gb1 = (const float*)d_in[4];
  const float* gw2 = (const float*)d_in[5];
  const float* gb2 = (const float*)d_in[6];
  const float* ew1 = (const float*)d_in[7];
  const float* eb1 = (const float*)d_in[8];
  const float* ew2 = (const float*)d_in[9];
  const float* eb2 = (const float*)d_in[10];

  if (ws_size < WS_NEED_2048) return;  // outputs stay poisoned -> loud failure signal
  const int HCcur = (ws_size >= WS_NEED_4096) ? 4096 : 2048;   // single-chunk if ws permits

  char* ws = (char*)d_ws;
  u16*   xbf   = (u16*)(ws + XBF_OFF);
  u16*   ew1t  = (u16*)(ws + EW1T_OFF);
  u16*   ew2t  = (u16*)(ws + EW2T_OFF);
  int*   tokl  = (int*)(ws + TOK_OFF);
  float* wtl   = (float*)(ws + WT_OFF);
  int*   cnts  = (int*)(ws + CNT_OFF);
  int*   basep = (int*)(ws + BASE_OFF);
  float* beff  = (float*)(ws + BEFF_OFF);
  float* hgate = (float*)(ws + HBUF_OFF);   // fp32 gate hidden, aliased with hbuf (consumed before FFN1)
  u16*   hbuf  = (u16*)(ws + HBUF_OFF);

  float* out    = (float*)d_out;
  float* scores = out + (size_t)T_TOK * DDIM;
  float* maskp  = scores + (size_t)T_TOK * NEXP;

  hipMemsetAsync(out, 0, (size_t)T_TOK * DDIM * sizeof(float), stream);  // atomics accumulate into this
  hipMemsetAsync(cnts, 0, NEXP * sizeof(int), stream);

  k_convert_x<<<2048, 256, 0, stream>>>(x, xbf, T_TOK * DDIM / 4);
  k_bias_eff<<<(DDIM + 255) / 256, 256, 0, stream>>>(gw1, gb1, snr, beff);
  k_transpose_bf16<<<dim3(DDIM / 64, HDIM / 64, NEXP), 256, 0, stream>>>(ew1, ew1t, DDIM, HDIM);
  k_transpose_bf16<<<dim3(HDIM / 64, DDIM / 64, NEXP), 256, 0, stream>>>(ew2, ew2t, HDIM, DDIM);
  k_gate_h<<<dim3(T_TOK / 128, DDIM / 128), 256, 0, stream>>>(x, gw1, beff, hgate);
  k_gate_logits<<<T_TOK / 4, 256, 0, stream>>>(hgate, gw2, gb2, gu, scores, maskp, tokl, wtl, cnts);
  k_scan<<<1, 64, 0, stream>>>(cnts, basep);

  for (int c = 0; c < HDIM / HCcur; c++) {
    k_ffn1<<<dim3(T_TOK / 128, HCcur / 128, NEXP), 256, 0, stream>>>(xbf, ew1t, eb1, tokl, cnts, basep, hbuf, c * HCcur, HCcur);
    k_ffn2<<<dim3(T_TOK / 128, DDIM / 128, NEXP), 256, 0, stream>>>(hbuf, ew2t, eb2, tokl, wtl, cnts, basep, out, c * HCcur, HCcur);
  }
}